// Round 2
// baseline (322.762 us; speedup 1.0000x reference)
//
#include <hip/hip_runtime.h>

#define DIM 768
#define TD 2304
#define NB 8
#define NS 4096
#define NE 6

// ws layout (float offsets)
#define OFF_QCATT  0            // [3][12][768] = 27648   (r<6: Q, r>=6: P), transposed [r][col]
#define OFF_AFOLD  27648        // [2304][12] = 27648     ([0:6]=A1 (colmean path), [6:12]=A2 (diff path))
#define OFF_GFULL  55296        // [224][6] = 1344        (Wglob @ Wroute[224:288])
#define OFF_CB0    56640        // [16]                   (all-bias constant, 6 used)
#define OFF_COLSUM 56656        // [8][2304] = 18432
#define OFF_CONSTB 75136        // [8][6] -> pad
#define OFF_QP     75264        // [3][8*4096][12] = 1179648
// total = 1,254,912 floats = 5.02 MB

// ---------------- kernel A: fold global path (Gfull, cb0) ----------------
__global__ __launch_bounds__(256) void k_fold0(
    const float* __restrict__ Wglob, const float* __restrict__ bglob,
    const float* __restrict__ Wroute, const float* __restrict__ broute,
    const float* __restrict__ bspat, const float* __restrict__ btemp,
    const float* __restrict__ bsync,
    float* __restrict__ Gfull, float* __restrict__ cb0)
{
    __shared__ float lwr[288 * NE];
    __shared__ float lgf[224 * NE];
    const int t = threadIdx.x;
    for (int i = t; i < 288 * NE; i += 256) lwr[i] = Wroute[i];
    __syncthreads();
    if (t < 224) {
        float g[NE] = {0, 0, 0, 0, 0, 0};
        for (int o = 0; o < 64; ++o) {
            const float w = Wglob[t * 64 + o];
            #pragma unroll
            for (int e = 0; e < NE; ++e) g[e] += w * lwr[(224 + o) * NE + e];
        }
        #pragma unroll
        for (int e = 0; e < NE; ++e) { Gfull[t * NE + e] = g[e]; lgf[t * NE + e] = g[e]; }
    }
    __syncthreads();
    if (t < NE) {
        float a = broute[t];
        for (int o = 0; o < 64; ++o)  a += bglob[o] * lwr[(224 + o) * NE + t];
        for (int o = 0; o < 128; ++o) a += bspat[o] * (lwr[o * NE + t] + lgf[o * NE + t]);
        for (int o = 0; o < 64; ++o)  a += btemp[o] * (lwr[(128 + o) * NE + t] + lgf[(128 + o) * NE + t]);
        for (int o = 0; o < 32; ++o)  a += bsync[o] * (lwr[(192 + o) * NE + t] + lgf[(192 + o) * NE + t]);
        cb0[t] = a;
    }
}

// ---------------- kernel B: fold per-column coefficients ----------------
__global__ __launch_bounds__(256) void k_fold(
    const float* __restrict__ Wspat, const float* __restrict__ Wtemp,
    const float* __restrict__ Wsync, const float* __restrict__ Wroute,
    const float* __restrict__ Gfull,
    float* __restrict__ QcatT, float* __restrict__ Afold)
{
    __shared__ float lwr[224 * NE];
    __shared__ float lgf[224 * NE];
    const int t = threadIdx.x;
    for (int i = t; i < 224 * NE; i += 256) { lwr[i] = Wroute[i]; lgf[i] = Gfull[i]; }
    __syncthreads();
    const int d = blockIdx.x * 256 + t;          // exactly 2304 threads
    const int st = d / DIM, dd = d - st * DIM;

    float p[NE] = {0, 0, 0, 0, 0, 0}, a2[NE] = {0, 0, 0, 0, 0, 0};
    for (int o = 0; o < 64; ++o) {
        const float w = Wtemp[d * 64 + o];
        #pragma unroll
        for (int e = 0; e < NE; ++e) {
            p[e]  += w * lwr[(128 + o) * NE + e];
            a2[e] += w * lgf[(128 + o) * NE + e];
        }
    }
    float qq[NE], a1[NE];
    #pragma unroll
    for (int e = 0; e < NE; ++e) { qq[e] = p[e]; a1[e] = 0.f; }
    for (int o = 0; o < 128; ++o) {
        const float w = Wspat[d * 128 + o];
        #pragma unroll
        for (int e = 0; e < NE; ++e) {
            qq[e] += w * lwr[o * NE + e];
            a1[e] += w * lgf[o * NE + e];
        }
    }
    if (st != 0) {
        const float sg = (st == 1) ? 1.f : -1.f;
        for (int o = 0; o < 32; ++o) {
            const float w = sg * Wsync[dd * 32 + o];
            #pragma unroll
            for (int e = 0; e < NE; ++e) {
                qq[e] += w * lwr[(192 + o) * NE + e];
                a1[e] += w * lgf[(192 + o) * NE + e];
            }
        }
    }
    #pragma unroll
    for (int e = 0; e < NE; ++e) {
        QcatT[(st * 12 + e) * DIM + dd]     = qq[e];
        QcatT[(st * 12 + 6 + e) * DIM + dd] = p[e];
        Afold[d * 12 + e]     = a1[e];
        Afold[d * 12 + 6 + e] = a2[e];
    }
}

// ---------------- kernel C: main streaming pass (barrier-free) ----------------
// grid = 8b * 3st * 32rg = 768 blocks, 256 thr = 4 waves, wave = 32 rows,
// lane: r8=l>>3 (4-row group), c4=l&7 (4-col quad); 24 steps of 32 cols.
__global__ __launch_bounds__(256, 3) void k_main(
    const float* __restrict__ xt, const float* __restrict__ xa, const float* __restrict__ xv,
    const float* __restrict__ QcatT, float* __restrict__ colsum, float* __restrict__ qp)
{
    __shared__ float swsum[DIM];
    const int t = threadIdx.x;
    const int w = t >> 6, l = t & 63;
    const int r8 = l >> 3, c4 = l & 7;
    const int bid = blockIdx.x;
    const int rg = bid & 31;
    const int st = (bid >> 5) % 3;
    const int b  = bid / 96;

    const float* X = (st == 0) ? xt : ((st == 1) ? xa : xv);
    const int row0 = rg * 128 + w * 32 + r8 * 4;
    const float* xbase = X + (b * NS + row0) * DIM + c4 * 4;
    const float* cbase = QcatT + st * 12 * DIM + c4 * 4;

    for (int i = t; i < DIM; i += 256) swsum[i] = 0.f;
    __syncthreads();

    float acc[4][12];
    #pragma unroll
    for (int k = 0; k < 4; ++k)
        #pragma unroll
        for (int r = 0; r < 12; ++r) acc[k][r] = 0.f;

    float4 A[4], B[4];

    auto loadx = [&](float4 (&buf)[4], int j) {
        const float* p = xbase + j * 32;
        buf[0] = *(const float4*)(p);
        buf[1] = *(const float4*)(p + DIM);
        buf[2] = *(const float4*)(p + 2 * DIM);
        buf[3] = *(const float4*)(p + 3 * DIM);
    };

    auto step = [&](float4 (&buf)[4], int j) {
        const int cb = j * 32;
        #pragma unroll
        for (int r = 0; r < 12; ++r) {
            const float4 cf = *(const float4*)(cbase + r * DIM + cb);
            #pragma unroll
            for (int k = 0; k < 4; ++k) {
                acc[k][r] += buf[k].x * cf.x;
                acc[k][r] += buf[k].y * cf.y;
                acc[k][r] += buf[k].z * cf.z;
                acc[k][r] += buf[k].w * cf.w;
            }
        }
        float s0 = buf[0].x + buf[1].x + buf[2].x + buf[3].x;
        float s1 = buf[0].y + buf[1].y + buf[2].y + buf[3].y;
        float s2 = buf[0].z + buf[1].z + buf[2].z + buf[3].z;
        float s3 = buf[0].w + buf[1].w + buf[2].w + buf[3].w;
        #pragma unroll
        for (int m = 8; m < 64; m <<= 1) {
            s0 += __shfl_xor(s0, m, 64);
            s1 += __shfl_xor(s1, m, 64);
            s2 += __shfl_xor(s2, m, 64);
            s3 += __shfl_xor(s3, m, 64);
        }
        if (l < 8) {
            atomicAdd(&swsum[cb + l * 4 + 0], s0);
            atomicAdd(&swsum[cb + l * 4 + 1], s1);
            atomicAdd(&swsum[cb + l * 4 + 2], s2);
            atomicAdd(&swsum[cb + l * 4 + 3], s3);
        }
    };

    loadx(A, 0);
    loadx(B, 1);
    for (int jj = 0; jj < 24; jj += 2) {
        step(A, jj);
        if (jj + 2 < 24) loadx(A, jj + 2);
        step(B, jj + 1);
        if (jj + 3 < 24) loadx(B, jj + 3);
    }

    // reduce partial dots across the 8 c4 lanes
    #pragma unroll
    for (int k = 0; k < 4; ++k)
        #pragma unroll
        for (int r = 0; r < 12; ++r) {
            float v = acc[k][r];
            v += __shfl_xor(v, 1, 64);
            v += __shfl_xor(v, 2, 64);
            v += __shfl_xor(v, 4, 64);
            acc[k][r] = v;
        }
    if (c4 == 0) {
        float* dst = qp + ((st * NB + b) * NS + row0) * 12;
        #pragma unroll
        for (int k = 0; k < 4; ++k) {
            *(float4*)(dst + k * 12 + 0) = make_float4(acc[k][0], acc[k][1], acc[k][2],  acc[k][3]);
            *(float4*)(dst + k * 12 + 4) = make_float4(acc[k][4], acc[k][5], acc[k][6],  acc[k][7]);
            *(float4*)(dst + k * 12 + 8) = make_float4(acc[k][8], acc[k][9], acc[k][10], acc[k][11]);
        }
    }

    __syncthreads();
    for (int i = t; i < DIM; i += 256)
        atomicAdd(&colsum[(b * 3 + st) * DIM + i], swsum[i]);
}

// ---------------- kernel D: per-batch global constant ----------------
__global__ __launch_bounds__(256) void k_const(
    const float* __restrict__ xt, const float* __restrict__ xa, const float* __restrict__ xv,
    const float* __restrict__ colsum, const float* __restrict__ Afold,
    const float* __restrict__ cb0, float* __restrict__ constb)
{
    const int b = blockIdx.x, t = threadIdx.x;
    const float* Xs[3] = { xt, xa, xv };
    float acc[NE] = {0, 0, 0, 0, 0, 0};
    const float inv = 1.f / 4096.f;
    for (int f = t; f < TD; f += 256) {
        const int st = f / DIM, dd = f - st * DIM;
        const float cm = colsum[b * TD + f] * inv;
        const float* Xp = Xs[st] + b * NS * DIM;
        const float dm = (Xp[(NS - 1) * DIM + dd] - Xp[dd]) * inv;
        const float* Ap = Afold + f * 12;
        #pragma unroll
        for (int e = 0; e < NE; ++e) acc[e] += cm * Ap[e] + dm * Ap[6 + e];
    }
    #pragma unroll
    for (int e = 0; e < NE; ++e)
        for (int m = 1; m < 64; m <<= 1) acc[e] += __shfl_xor(acc[e], m, 64);
    __shared__ float wred[4][NE];
    if ((t & 63) == 0) {
        #pragma unroll
        for (int e = 0; e < NE; ++e) wred[t >> 6][e] = acc[e];
    }
    __syncthreads();
    if (t < NE)
        constb[b * NE + t] = cb0[t] + wred[0][t] + wred[1][t] + wred[2][t] + wred[3][t];
}

// ---------------- kernel E: combine q - shifted p + const ----------------
__global__ __launch_bounds__(256) void k_add(
    const float* __restrict__ qp, const float* __restrict__ constb, float* __restrict__ out)
{
    const int row = blockIdx.x * 256 + threadIdx.x;   // 32768 rows exact
    const int b = row >> 12, s = row & (NS - 1);
    const int rowp = (s == 0) ? row : row - 1;
    float o[NE];
    #pragma unroll
    for (int e = 0; e < NE; ++e) o[e] = constb[b * NE + e];
    #pragma unroll
    for (int st = 0; st < 3; ++st) {
        const float* qr = qp + (st * NB * NS + row) * 12;
        const float* pr = qp + (st * NB * NS + rowp) * 12;
        #pragma unroll
        for (int e = 0; e < NE; ++e) o[e] += qr[e] - pr[6 + e];
    }
    float* op = out + row * NE;
    #pragma unroll
    for (int e = 0; e < NE; ++e) op[e] = o[e];
}

extern "C" void kernel_launch(void* const* d_in, const int* in_sizes, int n_in,
                              void* d_out, int out_size, void* d_ws, size_t ws_size,
                              hipStream_t stream)
{
    const float* xt     = (const float*)d_in[0];
    const float* xa     = (const float*)d_in[1];
    const float* xv     = (const float*)d_in[2];
    const float* Wspat  = (const float*)d_in[3];
    const float* bspat  = (const float*)d_in[4];
    const float* Wtemp  = (const float*)d_in[5];
    const float* btemp  = (const float*)d_in[6];
    const float* Wsync  = (const float*)d_in[7];
    const float* bsync  = (const float*)d_in[8];
    const float* Wglob  = (const float*)d_in[9];
    const float* bglob  = (const float*)d_in[10];
    const float* Wroute = (const float*)d_in[11];
    const float* broute = (const float*)d_in[12];
    float* out = (float*)d_out;

    float* ws     = (float*)d_ws;
    float* QcatT  = ws + OFF_QCATT;
    float* Afold  = ws + OFF_AFOLD;
    float* Gfull  = ws + OFF_GFULL;
    float* cb0    = ws + OFF_CB0;
    float* colsum = ws + OFF_COLSUM;
    float* constb = ws + OFF_CONSTB;
    float* qp     = ws + OFF_QP;

    hipMemsetAsync(colsum, 0, NB * TD * sizeof(float), stream);
    k_fold0<<<1, 256, 0, stream>>>(Wglob, bglob, Wroute, broute, bspat, btemp, bsync, Gfull, cb0);
    k_fold<<<9, 256, 0, stream>>>(Wspat, Wtemp, Wsync, Wroute, Gfull, QcatT, Afold);
    k_main<<<768, 256, 0, stream>>>(xt, xa, xv, QcatT, colsum, qp);
    k_const<<<8, 256, 0, stream>>>(xt, xa, xv, colsum, Afold, cb0, constb);
    k_add<<<128, 256, 0, stream>>>(qp, constb, out);
}